// Round 12
// baseline (102.543 us; speedup 1.0000x reference)
//
#include <hip/hip_runtime.h>
#include <hip/hip_bf16.h>
#include <stdint.h>

// Q8_0 dequant linear: y = x @ W^T + bias.  M=N=K=4096.
// INT8 path, OCCUPANCY-FIRST GEMM: 128x256 tile, BK=64, 64 KiB LDS
// (A double + B triple buffer) -> 2 blocks/CU, 4 waves/SIMD. Independent
// co-resident blocks overlap MFMA and LDS pipes without intra-block
// scheduling. Per wave per tile: 3 stage-gloads, 8 ds_reads, 16 MFMA,
// lgkm(0)+vmcnt(2)+barrier. XOR swizzle (bank-balanced), hoisted read bases.

#define M_DIM 4096
#define N_DIM 4096
#define K_DIM 4096
#define NB_SC 128

#define BM 128
#define BN 256
#define BKB 64                   // K-tile bytes (= elements, i8)
#define NT (K_DIM / BKB)         // 64 K-tiles
#define TILE_A (BM * BKB)        // 8 KiB
#define TILE_BN (BN * BKB)       // 16 KiB

typedef __attribute__((ext_vector_type(4))) int i32x4;

__device__ __forceinline__ void gload_lds16(const void* gsrc, void* ldsdst) {
  __builtin_amdgcn_global_load_lds(
      (__attribute__((address_space(1))) void*)(uintptr_t)gsrc,
      (__attribute__((address_space(3))) void*)(uint32_t)(uintptr_t)ldsdst,
      16, 0, 0);
}

__device__ __forceinline__ int pack4(int a, int b, int c, int d) {
  return (a & 255) | ((b & 255) << 8) | ((c & 255) << 16) | ((d & 255) << 24);
}

// ---------------- fused prep kernel (unchanged, verified) ----------------

__global__ void prep_kernel(const float* __restrict__ x, const int* __restrict__ q,
                            const float* __restrict__ sc,
                            char* __restrict__ xb, char* __restrict__ wb,
                            float* __restrict__ sxv, float* __restrict__ swv) {
  __shared__ float red[4];
  const int b = blockIdx.x;
  const int t = threadIdx.x;
  if (b < 4096) {
    const float4* row = (const float4*)(x + (size_t)b * K_DIM);
    float4 v[4];
    float m = 0.f;
#pragma unroll
    for (int i = 0; i < 4; ++i) {
      v[i] = row[t * 4 + i];
      m = fmaxf(m, fmaxf(fmaxf(fabsf(v[i].x), fabsf(v[i].y)),
                         fmaxf(fabsf(v[i].z), fabsf(v[i].w))));
    }
#pragma unroll
    for (int off = 32; off >= 1; off >>= 1) m = fmaxf(m, __shfl_xor(m, off, 64));
    if ((t & 63) == 0) red[t >> 6] = m;
    __syncthreads();
    m = fmaxf(fmaxf(red[0], red[1]), fmaxf(red[2], red[3]));
    const float inv = (m > 0.f) ? 127.0f / m : 0.f;
    int4 o;
    o.x = pack4(__float2int_rn(v[0].x * inv), __float2int_rn(v[0].y * inv),
                __float2int_rn(v[0].z * inv), __float2int_rn(v[0].w * inv));
    o.y = pack4(__float2int_rn(v[1].x * inv), __float2int_rn(v[1].y * inv),
                __float2int_rn(v[1].z * inv), __float2int_rn(v[1].w * inv));
    o.z = pack4(__float2int_rn(v[2].x * inv), __float2int_rn(v[2].y * inv),
                __float2int_rn(v[2].z * inv), __float2int_rn(v[2].w * inv));
    o.w = pack4(__float2int_rn(v[3].x * inv), __float2int_rn(v[3].y * inv),
                __float2int_rn(v[3].z * inv), __float2int_rn(v[3].w * inv));
    ((int4*)(xb + (size_t)b * K_DIM))[t] = o;
    if (t == 0) sxv[b] = m / 127.0f;
  } else {
    const int o_row = b - 4096;
    float m = sc[o_row * NB_SC + (t & 127)];
#pragma unroll
    for (int off = 32; off >= 1; off >>= 1) m = fmaxf(m, __shfl_xor(m, off, 64));
    if ((t & 63) == 0) red[t >> 6] = m;
    __syncthreads();
    m = fmaxf(fmaxf(red[0], red[1]), fmaxf(red[2], red[3]));
    const float ratio = sc[o_row * NB_SC + (t >> 1)] / m;   // scales >= 1e-4 > 0
    const int4* qp = (const int4*)(q + (size_t)o_row * K_DIM);
    int4 qv[4];
#pragma unroll
    for (int i = 0; i < 4; ++i) qv[i] = qp[t * 4 + i];
    int4 ov;
    ov.x = pack4(__float2int_rn((float)qv[0].x * ratio), __float2int_rn((float)qv[0].y * ratio),
                 __float2int_rn((float)qv[0].z * ratio), __float2int_rn((float)qv[0].w * ratio));
    ov.y = pack4(__float2int_rn((float)qv[1].x * ratio), __float2int_rn((float)qv[1].y * ratio),
                 __float2int_rn((float)qv[1].z * ratio), __float2int_rn((float)qv[1].w * ratio));
    ov.z = pack4(__float2int_rn((float)qv[2].x * ratio), __float2int_rn((float)qv[2].y * ratio),
                 __float2int_rn((float)qv[2].z * ratio), __float2int_rn((float)qv[2].w * ratio));
    ov.w = pack4(__float2int_rn((float)qv[3].x * ratio), __float2int_rn((float)qv[3].y * ratio),
                 __float2int_rn((float)qv[3].z * ratio), __float2int_rn((float)qv[3].w * ratio));
    ((int4*)(wb + (size_t)o_row * K_DIM))[t] = ov;
    if (t == 0) swv[o_row] = m;
  }
}

// ---------------- 128x256 BK=64 i8 GEMM, 2 blocks/CU ----------------
// LDS rows are 64 B = 4 x 16B granules. Logical granule g of row r stored at
// g ^ s(r), s(r) = (r&3)^((r>>2)&3)  (involution; invariant under row steps
// of 16 -> read bases hoist with imm offsets; bank load balanced 8/bank).

// Stage one 128-row unit (8 KiB): 1 gload/wave. Lane l -> row l>>2, dst
// granule l&3; source granule (l&3)^s(l>>2) pre-applied in pX.
__device__ __forceinline__ void stage_unit(const char* __restrict__ pX,
                                           char* ldsdst, int w) {
  gload_lds16(pX, ldsdst + w * 1024);
}

__device__ __forceinline__ void mfma_all(const i32x4 (&af)[4], const i32x4 (&bf)[4],
                                         i32x4 (&acc)[4][4]) {
  __builtin_amdgcn_s_setprio(1);
#pragma unroll
  for (int a = 0; a < 4; ++a)
#pragma unroll
    for (int b = 0; b < 4; ++b)
      acc[a][b] = __builtin_amdgcn_mfma_i32_16x16x64_i8(af[a], bf[b], acc[a][b], 0, 0, 0);
  __builtin_amdgcn_s_setprio(0);
}

// AB = t&1, BB = t%3.  Reads A[AB], B[BB]; writes A[AB^1]=A(t+1),
// B[(BB+2)%3]=B(t+2) — disjoint from all same-tile reads.
// MODE: 0 steady; 1 = t==NT-2 (A(t+1) stage only, vmcnt(0)); 2 = last tile.
template <int AB, int BB, int MODE>
__device__ __forceinline__ void ktile(const char* pa, const char* pb,
                                      const char* __restrict__ pA,
                                      const char* __restrict__ pB,
                                      char* AsB, char* BsB,
                                      int ktb, int w,
                                      i32x4 (&acc)[4][4]) {
  // stages first: stream into LDS while we read+compute
  if (MODE < 2)
    stage_unit(pA + ktb + BKB, AsB + (AB ^ 1) * TILE_A, w);
  if (MODE == 0) {
#pragma unroll
    for (int u = 0; u < 2; ++u)
      stage_unit(pB + (size_t)u * 128 * K_DIM + ktb + 2 * BKB,
                 BsB + ((BB + 2) % 3) * TILE_BN + u * 8192, w);
  }

  // 8 ds_reads + 16 MFMAs (compiler-counted lgkm)
  i32x4 af[4], bf[4];
#pragma unroll
  for (int f = 0; f < 4; ++f)
    bf[f] = *(const i32x4*)(pb + BB * TILE_BN + f * 1024);
#pragma unroll
  for (int f = 0; f < 4; ++f)
    af[f] = *(const i32x4*)(pa + AB * TILE_A + f * 1024);
  mfma_all(af, bf, acc);

  // boundary: own reads done, then A(t+1)/B(t+1) landed, converge
  if (MODE < 2) {
    asm volatile("s_waitcnt lgkmcnt(0)" ::: "memory");
    if (MODE == 0)
      asm volatile("s_waitcnt vmcnt(2)" ::: "memory");  // leaves B(t+2) in flight
    else
      asm volatile("s_waitcnt vmcnt(0)" ::: "memory");
    __builtin_amdgcn_s_barrier();
    __builtin_amdgcn_sched_barrier(0);
  }
}

__global__ __launch_bounds__(512, 4) void gemm128(const char* __restrict__ A,
                                                  const char* __restrict__ B,
                                                  const float* __restrict__ sxv,
                                                  const float* __restrict__ swv,
                                                  const float* __restrict__ bias,
                                                  float* __restrict__ C) {
  __shared__ char AsB[2 * TILE_A];    // 16 KiB
  __shared__ char BsB[3 * TILE_BN];   // 48 KiB  -> 64 KiB total, 2 blocks/CU

  const int tid = threadIdx.x;
  const int w = tid >> 6;
  const int l = tid & 63;
  const int wm = w >> 2;            // 2 x 4 waves, each owns 64x64 output
  const int wn = w & 3;
  const int frow = l & 15;
  const int gl = l >> 4;            // K-granule 0..3

  const int bid = blockIdx.x;
  const int cpx = gridDim.x >> 3;   // 512 % 8 == 0 -> bijective
  const int swz = (bid & 7) * cpx + (bid >> 3);
  const int bm0 = (swz >> 4) * BM;  // 32 M-tiles
  const int bn0 = (swz & 15) * BN;  // 16 N-tiles

  // hoisted lane-constant LDS read bases: row = base + f*16 + frow,
  // s(row) = (frow&3)^((frow>>2)&3) invariant under +16 steps
  const int srow = (frow & 3) ^ ((frow >> 2) & 3);
  const int swg = ((gl ^ srow) << 4);
  const char* pa = (const char*)AsB + (wm * 64 + frow) * BKB + swg;
  const char* pb = (const char*)BsB + (wn * 64 + frow) * BKB + swg;

  // lane-constant global stage bases: lane l -> row l>>2, src granule
  // (l&3) ^ s(row) = (l&3)^((l>>2)&3)^((l>>4)&3)
  const int sr = l >> 2;
  const int skp = ((((l & 3) ^ ((l >> 2) & 3)) ^ ((l >> 4) & 3)) << 4);
  const char* pA = A + (size_t)(bm0 + w * 16 + sr) * K_DIM + skp;
  const char* pB = B + (size_t)(bn0 + w * 16 + sr) * K_DIM + skp;

  i32x4 acc[4][4] = {};

  // Prologue: A(0), B(0) u0+u1, B(1) u0+u1 (5 loads/wave); vmcnt(2):
  // A(0)+B(0) landed, B(1)'s 2 in flight (steady-state invariant).
  stage_unit(pA, AsB, w);
  stage_unit(pB, BsB, w);
  stage_unit(pB + (size_t)128 * K_DIM, BsB + 8192, w);
  stage_unit(pB + BKB, BsB + TILE_BN, w);
  stage_unit(pB + (size_t)128 * K_DIM + BKB, BsB + TILE_BN + 8192, w);
  asm volatile("s_waitcnt vmcnt(2)" ::: "memory");
  __builtin_amdgcn_s_barrier();

  // 6-unrolled main loop (lcm(2,3)): tiles 0..59, then 4 peeled
  for (int t = 0; t < NT - 4; t += 6) {
    ktile<0, 0, 0>(pa, pb, pA, pB, AsB, BsB, (t + 0) * BKB, w, acc);
    ktile<1, 1, 0>(pa, pb, pA, pB, AsB, BsB, (t + 1) * BKB, w, acc);
    ktile<0, 2, 0>(pa, pb, pA, pB, AsB, BsB, (t + 2) * BKB, w, acc);
    ktile<1, 0, 0>(pa, pb, pA, pB, AsB, BsB, (t + 3) * BKB, w, acc);
    ktile<0, 1, 0>(pa, pb, pA, pB, AsB, BsB, (t + 4) * BKB, w, acc);
    ktile<1, 2, 0>(pa, pb, pA, pB, AsB, BsB, (t + 5) * BKB, w, acc);
  }
  ktile<0, 0, 0>(pa, pb, pA, pB, AsB, BsB, (NT - 4) * BKB, w, acc);
  ktile<1, 1, 0>(pa, pb, pA, pB, AsB, BsB, (NT - 3) * BKB, w, acc);
  ktile<0, 2, 1>(pa, pb, pA, pB, AsB, BsB, (NT - 2) * BKB, w, acc);
  ktile<1, 0, 2>(pa, pb, pA, pB, AsB, BsB, (NT - 1) * BKB, w, acc);

  // Epilogue: y = s_x[m]*s_w[n]*acc + bias[n]; C/D col=l&15, row=(l>>4)*4+r
#pragma unroll
  for (int nb = 0; nb < 4; ++nb) {
    const int n = bn0 + wn * 64 + nb * 16 + (l & 15);
    const float swn = swv[n];
    const float bv = bias[n];
#pragma unroll
    for (int ma = 0; ma < 4; ++ma) {
      const int mbase = bm0 + wm * 64 + ma * 16 + (l >> 4) * 4;
#pragma unroll
      for (int r = 0; r < 4; ++r)
        C[(size_t)(mbase + r) * N_DIM + n] =
            (float)acc[ma][nb][r] * (swn * sxv[mbase + r]) + bv;
    }
  }
}

// ---------------- naive fallback ----------------

__global__ void naive_kernel(const float* __restrict__ x, const int* __restrict__ q,
                             const float* __restrict__ sc, const float* __restrict__ bias,
                             float* __restrict__ out) {
  size_t idx = (size_t)blockIdx.x * blockDim.x + threadIdx.x;
  if (idx >= (size_t)M_DIM * N_DIM) return;
  int n = (int)(idx & (N_DIM - 1));
  size_t m = idx >> 12;
  float acc = 0.f;
  for (int k = 0; k < K_DIM; k += 32) {
    float s = sc[n * NB_SC + (k >> 5)];
    float part = 0.f;
    for (int j = 0; j < 32; ++j)
      part += x[m * K_DIM + k + j] * (float)q[(size_t)n * K_DIM + k + j];
    acc += part * s;
  }
  out[idx] = acc + bias[n];
}

// ---------------- launch ----------------

extern "C" void kernel_launch(void* const* d_in, const int* in_sizes, int n_in,
                              void* d_out, int out_size, void* d_ws, size_t ws_size,
                              hipStream_t stream) {
  const float* x    = (const float*)d_in[0];
  const int*   q    = (const int*)d_in[1];
  const float* sc   = (const float*)d_in[2];
  const float* bias = (const float*)d_in[3];
  float* out = (float*)d_out;

  const size_t elems = (size_t)M_DIM * K_DIM;
  const size_t need  = 2 * elems + 2 * 4096 * sizeof(float);

  if (ws_size >= need) {
    char* xb = (char*)d_ws;
    char* wb = xb + elems;
    float* sxv = (float*)(wb + elems);
    float* swv = sxv + 4096;
    hipLaunchKernelGGL(prep_kernel, dim3(8192), dim3(256), 0, stream,
                       x, q, sc, xb, wb, sxv, swv);
    hipLaunchKernelGGL(gemm128, dim3((M_DIM / BM) * (N_DIM / BN)), dim3(512), 0, stream,
                       xb, wb, sxv, swv, bias, out);
  } else {
    hipLaunchKernelGGL(naive_kernel, dim3((M_DIM * N_DIM) / 256), dim3(256), 0, stream,
                       x, q, sc, bias, out);
  }
}